// Round 10
// baseline (190.843 us; speedup 1.0000x reference)
//
#include <hip/hip_runtime.h>
#include <hip/hip_bf16.h>

#define BB 16
#define NN 512
#define DD 64
#define BN_ROWS (BB * NN)   // 8192
#define NBIN 32             // stats bins (atomic chain depth 8192/32 = 256)

typedef unsigned short ushort;
typedef unsigned int uint;
typedef short bf16x8 __attribute__((ext_vector_type(8)));   // 8 bf16 = 4 VGPRs
typedef float f32x4  __attribute__((ext_vector_type(4)));   // MFMA acc

#define K2LOG2E 2.885390081777927f   // 2 * log2(e)

// ws layout: stats[NBIN*128] | wpf fp32 frag-ordered [4096] | xbf bf16 [524288]
// R37 = R36 with three independent single-kernel tweaks:
//  - prep: 131072 threads (grid 512), one float4 -> one uint2 each: 2x TLP
//    (8 waves/CU) on the latency-bound reshuffle.
//  - final: bin reduction parallelized across 256 threads (16 bins/thread,
//    LDS combine) instead of 64 threads x 32 serial loads.
//  - attn: s_setprio(1/0) around the MFMA+sigr cluster (T5 regime: many
//    independent blocks at different phases).
// Decision rule: if total stays ~180, the ~59us non-attn is launch/gap
// overhead -> next round is the persistent single-kernel design.

__device__ __forceinline__ uint pkbf2(float lo, float hi) {
    union { float f; uint u; } a, b; a.f = lo; b.f = hi;
    return __builtin_amdgcn_perm(b.u + 0x8000u, a.u + 0x8000u, 0x07060302u);
}
__device__ __forceinline__ float bflo(uint u) {
    union { uint i; float f; } c; c.i = u << 16; return c.f;
}
__device__ __forceinline__ float bfhi(uint u) {
    union { uint i; float f; } c; c.i = u & 0xffff0000u; return c.f;
}
// r = 1/(2^x + 1); caller folds tanh contribution as s += awk * r.
__device__ __forceinline__ float sigr(float x) {
    return __builtin_amdgcn_rcpf(__builtin_amdgcn_exp2f(x) + 1.0f);
}

// One-time: x -> bf16 B-frag order; Wp -> fp32 A-frag order (pre-scaled by
// 2*log2e); zero stats bins.  131072 threads, one uint2 out each.
__global__ __launch_bounds__(256) void prep_kernel(
    const float* __restrict__ x, const float* __restrict__ Wp,
    float* __restrict__ wpf, ushort* __restrict__ xbf, float* __restrict__ stats)
{
    const int tid = blockIdx.x * 256 + threadIdx.x;     // grid 512 -> 0..131071
    const int tid16 = tid >> 1, sub = tid & 1;          // old-uint4 id, half
    const int b = tid16 >> 12, rem = tid16 & 4095;
    const int jt = rem >> 7, ks = (rem >> 6) & 1, lane = rem & 63;
    const int qd = lane >> 4, ln = lane & 15;
    const float* __restrict__ src =
        x + ((size_t)(b * NN + jt * 16 + ln)) * DD + ks * 32 + qd * 8 + sub * 4;
    const float4 v = *(const float4*)src;
    uint2 o;
    o.x = pkbf2(v.x, v.y); o.y = pkbf2(v.z, v.w);
    ((uint2*)xbf)[tid] = o;                              // coalesced 8B
    if (tid < DD * DD) {
        const int oo = tid >> 6, d = tid & 63;
        const int mt = oo >> 4, l2 = oo & 15;
        const int k2 = d >> 5, q2 = (d >> 3) & 3, e = d & 7;
        wpf[(((mt * 2 + k2) * 64) + (q2 * 16 + l2)) * 8 + e] = Wp[tid] * K2LOG2E;
    }
    if (tid < NBIN * 128) stats[tid] = 0.0f;
}

// One block (256 thr, 4 waves) per (b,i); wave wv owns j-tiles wv*8..wv*8+7.
// XCD swizzle: b = (blk&7)*2 + ((blk>>3)&1), i = blk>>4.
// Computes agg, then the projection tail in-block -> pre-BN out + binned stats.
template <int MINW>
__global__ __launch_bounds__(256, MINW) void attn_kernel(
    const float* __restrict__ x,  const float* __restrict__ wpf,
    const ushort* __restrict__ xbf,
    const float* __restrict__ bp, const float* __restrict__ aw,
    const float* __restrict__ W1, const float* __restrict__ b1,
    const float* __restrict__ W2, const float* __restrict__ b2,
    float* __restrict__ out, float* __restrict__ stats)
{
    __shared__ float part[4][DD];                   // 1 KB
    __shared__ float s_esum[4];
    __shared__ __align__(16) float s_agg[DD], s_xi[DD];

    const int t = threadIdx.x;                      // 0..255
    const int wv = t >> 6, lane = t & 63;
    const int blk = blockIdx.x;                     // 0..8191
    const int b = (blk & 7) * 2 + ((blk >> 3) & 1); // XCD-local b
    const int i = blk >> 4;                         // 0..511
    const int row = b * NN + i;
    const int qd = lane >> 4, ln = lane & 15;
    const ushort* __restrict__ xb16 = xbf + (size_t)b * (NN * DD);
    const float* __restrict__ xrow = x + (size_t)row * DD;

    if (t < DD) s_xi[t] = xrow[t];                  // for the projection tail

    // xi fragment straight from global (L1/L2-hot; per-quad broadcast)
    float xiv[2][8];
    #pragma unroll
    for (int ks = 0; ks < 2; ++ks) {
        const float4 a = *(const float4*)(xrow + ks * 32 + qd * 8);
        const float4 c = *(const float4*)(xrow + ks * 32 + qd * 8 + 4);
        xiv[ks][0]=a.x; xiv[ks][1]=a.y; xiv[ks][2]=a.z; xiv[ks][3]=a.w;
        xiv[ks][4]=c.x; xiv[ks][5]=c.y; xiv[ks][6]=c.z; xiv[ks][7]=c.w;
    }

    // bpk/awk straight from global (512B, L1-hot across all blocks)
    float bpk[16], awk[16];
    #pragma unroll
    for (int mt = 0; mt < 4; ++mt) {
        const float4 vb = *(const float4*)(bp + mt * 16 + qd * 4);
        const float4 va = *(const float4*)(aw + mt * 16 + qd * 4);
        bpk[mt*4+0] = vb.x * K2LOG2E; bpk[mt*4+1] = vb.y * K2LOG2E;
        bpk[mt*4+2] = vb.z * K2LOG2E; bpk[mt*4+3] = vb.w * K2LOG2E;
        awk[mt*4+0] = va.x * -K2LOG2E; awk[mt*4+1] = va.y * -K2LOG2E;
        awk[mt*4+2] = va.z * -K2LOG2E; awk[mt*4+3] = va.w * -K2LOG2E;
    }

    // A-frags: (2log2e * Wp) ⊙ xi in bf16, g = mt*2+ks
    bf16x8 afrag[8];
    #pragma unroll
    for (int g = 0; g < 8; ++g) {
        const int ks = g & 1;
        const float4 wa = *(const float4*)(wpf + (g * 64 + lane) * 8);
        const float4 wb = *(const float4*)(wpf + (g * 64 + lane) * 8 + 4);
        union { bf16x8 v; uint u[4]; } p;
        p.u[0] = pkbf2(wa.x * xiv[ks][0], wa.y * xiv[ks][1]);
        p.u[1] = pkbf2(wa.z * xiv[ks][2], wa.w * xiv[ks][3]);
        p.u[2] = pkbf2(wb.x * xiv[ks][4], wb.y * xiv[ks][5]);
        p.u[3] = pkbf2(wb.z * xiv[ks][6], wb.w * xiv[ks][7]);
        afrag[g] = p.v;
    }

    // ---- FUSED score + aggregate: 8 j-tiles for this wave ----
    float vacc[16];
    #pragma unroll
    for (int k = 0; k < 16; ++k) vacc[k] = 0.0f;
    float esum = 0.0f;

    #pragma unroll 4
    for (int tt = 0; tt < 8; ++tt) {
        const int tile = wv * 8 + tt;
        union { bf16x8 v; uint4 u; } b0, b1u;
        b0.v  = *(const bf16x8*)(xb16 + ((tile * 2 + 0) * 64 + lane) * 8);
        b1u.v = *(const bf16x8*)(xb16 + ((tile * 2 + 1) * 64 + lane) * 8);

        float s0 = 0.0f, s1 = 0.0f, s2 = 0.0f, s3 = 0.0f;
        __builtin_amdgcn_s_setprio(1);
        #pragma unroll
        for (int mt = 0; mt < 4; ++mt) {
            f32x4 acc = { bpk[mt*4+0], bpk[mt*4+1], bpk[mt*4+2], bpk[mt*4+3] };
            acc = __builtin_amdgcn_mfma_f32_16x16x32_bf16(afrag[mt*2+0], b0.v,  acc, 0, 0, 0);
            acc = __builtin_amdgcn_mfma_f32_16x16x32_bf16(afrag[mt*2+1], b1u.v, acc, 0, 0, 0);
            s0 = fmaf(awk[mt*4+0], sigr(acc[0]), s0);
            s1 = fmaf(awk[mt*4+1], sigr(acc[1]), s1);
            s2 = fmaf(awk[mt*4+2], sigr(acc[2]), s2);
            s3 = fmaf(awk[mt*4+3], sigr(acc[3]), s3);
        }
        __builtin_amdgcn_s_setprio(0);
        float sj = (s0 + s1) + (s2 + s3);
        sj += __shfl_xor(sj, 16);
        sj += __shfl_xor(sj, 32);        // all quads: exp2-arg for j = tile*16 + ln

        const float e = __builtin_amdgcn_exp2f(sj);   // log2e folded into awk
        esum += e;
        vacc[0]  = fmaf(e, bflo(b0.u.x),  vacc[0]);
        vacc[1]  = fmaf(e, bfhi(b0.u.x),  vacc[1]);
        vacc[2]  = fmaf(e, bflo(b0.u.y),  vacc[2]);
        vacc[3]  = fmaf(e, bfhi(b0.u.y),  vacc[3]);
        vacc[4]  = fmaf(e, bflo(b0.u.z),  vacc[4]);
        vacc[5]  = fmaf(e, bfhi(b0.u.z),  vacc[5]);
        vacc[6]  = fmaf(e, bflo(b0.u.w),  vacc[6]);
        vacc[7]  = fmaf(e, bfhi(b0.u.w),  vacc[7]);
        vacc[8]  = fmaf(e, bflo(b1u.u.x), vacc[8]);
        vacc[9]  = fmaf(e, bfhi(b1u.u.x), vacc[9]);
        vacc[10] = fmaf(e, bflo(b1u.u.y), vacc[10]);
        vacc[11] = fmaf(e, bfhi(b1u.u.y), vacc[11]);
        vacc[12] = fmaf(e, bflo(b1u.u.z), vacc[12]);
        vacc[13] = fmaf(e, bfhi(b1u.u.z), vacc[13]);
        vacc[14] = fmaf(e, bflo(b1u.u.w), vacc[14]);
        vacc[15] = fmaf(e, bfhi(b1u.u.w), vacc[15]);
    }

    // reduce over ln within wave
    #pragma unroll
    for (int off = 1; off < 16; off <<= 1) {
        esum += __shfl_xor(esum, off);
        #pragma unroll
        for (int k = 0; k < 16; ++k)
            vacc[k] += __shfl_xor(vacc[k], off);
    }
    if (lane == 0) s_esum[wv] = esum;
    if (ln == 0) {
        #pragma unroll
        for (int k = 0; k < 16; ++k)
            part[wv][(k >> 3) * 32 + qd * 8 + (k & 7)] = vacc[k];
    }
    __syncthreads();

    // block combine: agg[d] = (Σ_wv part[wv][d]) / (Σ_wv esum[wv]) -> s_agg
    if (t < DD) {
        const float tot = (s_esum[0] + s_esum[1]) + (s_esum[2] + s_esum[3]);
        const float inv = 1.0f / tot;
        const float a = (part[0][t] + part[1][t]) + (part[2][t] + part[3][t]);
        s_agg[t] = a * inv;
    }
    __syncthreads();

    // ---- projection tail (was proj_kernel) ----
    // thread (o = t>>2, qq = t&3): 16-d partial; W reads coalesced (wave =
    // 16 rows x 256B = 4KB contiguous); s_agg/s_xi reads are broadcasts.
    {
        const int o = t >> 2, qq = t & 3, d0 = qq * 16;
        const float* __restrict__ w1r = W1 + o * DD + d0;
        const float* __restrict__ w2r = W2 + o * DD + d0;
        float v = 0.0f;
        #pragma unroll
        for (int h = 0; h < 2; ++h) {       // 8 d's at a time, caps live regs
            const int dd = h * 8;
            const float4 wa  = *(const float4*)(w1r + dd);
            const float4 wa2 = *(const float4*)(w1r + dd + 4);
            const float4 ag  = *(const float4*)(s_agg + d0 + dd);
            const float4 ag2 = *(const float4*)(s_agg + d0 + dd + 4);
            v = fmaf(wa.x,  ag.x,  v); v = fmaf(wa.y,  ag.y,  v);
            v = fmaf(wa.z,  ag.z,  v); v = fmaf(wa.w,  ag.w,  v);
            v = fmaf(wa2.x, ag2.x, v); v = fmaf(wa2.y, ag2.y, v);
            v = fmaf(wa2.z, ag2.z, v); v = fmaf(wa2.w, ag2.w, v);
            const float4 wb  = *(const float4*)(w2r + dd);
            const float4 wb2 = *(const float4*)(w2r + dd + 4);
            const float4 xi  = *(const float4*)(s_xi + d0 + dd);
            const float4 xi2 = *(const float4*)(s_xi + d0 + dd + 4);
            v = fmaf(wb.x,  xi.x,  v); v = fmaf(wb.y,  xi.y,  v);
            v = fmaf(wb.z,  xi.z,  v); v = fmaf(wb.w,  xi.w,  v);
            v = fmaf(wb2.x, xi2.x, v); v = fmaf(wb2.y, xi2.y, v);
            v = fmaf(wb2.z, xi2.z, v); v = fmaf(wb2.w, xi2.w, v);
        }
        v += __shfl_xor(v, 1);
        v += __shfl_xor(v, 2);              // qq==0 lanes hold full 64-d sum
        if (qq == 0) {
            v += b1[o] + b2[o];
            out[(size_t)row * DD + o] = v;  // pre-BN x_out
            float* __restrict__ sb = stats + (blk & (NBIN - 1)) * 128;
            atomicAdd(&sb[o], v);
            atomicAdd(&sb[64 + o], v * v);
        }
    }
}

// BN (batch stats, biased var) + selu, IN PLACE on out; float4 I/O.
// Bin reduction parallel across 256 threads (16 bins each), LDS combine.
__global__ __launch_bounds__(256) void final_kernel(
    const float* __restrict__ stats,
    const float* __restrict__ gamma, const float* __restrict__ beta,
    float* __restrict__ out)
{
    __shared__ float red[2][128];
    __shared__ float smu[DD], sga[DD], sbe[DD];
    {
        const int slot = threadIdx.x & 127, grp = threadIdx.x >> 7;  // 0/1
        float s = 0.0f;
        #pragma unroll
        for (int bb = 0; bb < NBIN / 2; ++bb)
            s += stats[(grp * (NBIN / 2) + bb) * 128 + slot];
        red[grp][slot] = s;
    }
    __syncthreads();
    if (threadIdx.x < DD) {
        const int o = threadIdx.x;
        const float s1 = red[0][o] + red[1][o];
        const float s2 = red[0][64 + o] + red[1][64 + o];
        const float mean = s1 * (1.0f / BN_ROWS);
        const float var  = s2 * (1.0f / BN_ROWS) - mean * mean;
        smu[o] = mean;
        sga[o] = gamma[o] / sqrtf(var + 1e-5f);
        sbe[o] = beta[o];
    }
    __syncthreads();
    const int i4 = blockIdx.x * 256 + threadIdx.x;   // grid 512 -> exactly 131072
    const int o0 = (i4 & 15) * 4;
    const float4 v = ((const float4*)out)[i4];
    float r[4] = { v.x, v.y, v.z, v.w };
    #pragma unroll
    for (int c = 0; c < 4; ++c) {
        const float nrm = (r[c] - smu[o0 + c]) * sga[o0 + c] + sbe[o0 + c];
        r[c] = nrm > 0.0f
            ? 1.0507009873554805f * nrm
            : 1.7580993408473766f * expm1f(nrm);
    }
    ((float4*)out)[i4] = make_float4(r[0], r[1], r[2], r[3]);
}

extern "C" void kernel_launch(void* const* d_in, const int* in_sizes, int n_in,
                              void* d_out, int out_size, void* d_ws, size_t ws_size,
                              hipStream_t stream)
{
    const float* x  = (const float*)d_in[0];
    const float* Wp = (const float*)d_in[1];  // W_att_proj
    const float* bp = (const float*)d_in[2];  // b_att_proj
    const float* aw = (const float*)d_in[3];  // att_weight
    const float* W1 = (const float*)d_in[4];  // W_with
    const float* b1 = (const float*)d_in[5];  // b_with
    const float* W2 = (const float*)d_in[6];  // W_without
    const float* b2 = (const float*)d_in[7];  // b_without
    const float* ga = (const float*)d_in[8];  // gamma
    const float* be = (const float*)d_in[9];  // beta

    float*  stats = (float*)d_ws;                       // NBIN*128 floats (16KB)
    float*  wpf   = stats + NBIN * 128;                 // 4096 fp32 (A-frag order)
    ushort* xbf   = (ushort*)(wpf + DD * DD);           // 524288 bf16 (B-frag order)
    float*  out   = (float*)d_out;                      // fp32 output

    // cascade: highest min-waves instantiation that compiled spill-free.
    typedef void (*attn_fn)(const float*, const float*, const ushort*,
                            const float*, const float*,
                            const float*, const float*,
                            const float*, const float*,
                            float*, float*);
    static attn_fn chosen = nullptr;
    if (!chosen) {
        attn_fn cands[4] = { attn_kernel<7>, attn_kernel<6>,
                             attn_kernel<5>, attn_kernel<3> };
        chosen = cands[3];                 // safe default
        for (int c = 0; c < 4; ++c) {
            hipFuncAttributes fa;
            if (hipFuncGetAttributes(&fa,
                    reinterpret_cast<const void*>(cands[c])) == hipSuccess
                && fa.localSizeBytes == 0) {
                chosen = cands[c];
                break;
            }
        }
    }

    prep_kernel<<<512, 256, 0, stream>>>(x, Wp, wpf, xbf, stats);
    chosen<<<BN_ROWS, 256, 0, stream>>>(x, wpf, xbf, bp, aw, W1, b1, W2, b2, out, stats);
    final_kernel<<<512, 256, 0, stream>>>(stats, ga, be, out);
}

// Round 11
// 182.348 us; speedup vs baseline: 1.0466x; 1.0466x over previous
//
#include <hip/hip_runtime.h>
#include <hip/hip_bf16.h>

#define BB 16
#define NN 512
#define DD 64
#define BN_ROWS (BB * NN)   // 8192
#define NBIN 32             // stats bins (atomic chain depth 8192/32 = 256)

typedef unsigned short ushort;
typedef unsigned int uint;
typedef short bf16x8 __attribute__((ext_vector_type(8)));   // 8 bf16 = 4 VGPRs
typedef float f32x4  __attribute__((ext_vector_type(4)));   // MFMA acc

#define K2LOG2E 2.885390081777927f   // 2 * log2(e)

// ws layout: stats[NBIN*128] | wpf fp32 frag-ordered [4096] | xbf bf16 [524288]
// R38 = R36 (183.2us proven base) with:
//  - setprio REVERTED (R37 A/B: cost 9us on attn).
//  - occupancy reclaim: R36's tail fusion pushed VGPR 72->76, crossing the
//    73=512/7 boundary -> cascade fell from <7> to <6> waves/SIMD. New
//    <8>-eligible body (cap 64): awk[16] moved to LDS, re-read per use via
//    VOLATILE ds_read (plain reads would be LICM-hoisted back to registers).
//    Only instantiated for MINW>=8 (if constexpr); cascade {8,7,6,5,3}
//    falls back to the proven register body if <8> spills (R29/R33 rule:
//    cap < demand => allocator collapse, so never force it).
//  - prep (2x TLP) / final (parallel bin reduce) kept from R37 (neutral).
// Non-attn residue ~58us is launch/graph overhead (R37 decision rule:
// unresponsive to prep/final tuning) — not chased further.

__device__ __forceinline__ uint pkbf2(float lo, float hi) {
    union { float f; uint u; } a, b; a.f = lo; b.f = hi;
    return __builtin_amdgcn_perm(b.u + 0x8000u, a.u + 0x8000u, 0x07060302u);
}
__device__ __forceinline__ float bflo(uint u) {
    union { uint i; float f; } c; c.i = u << 16; return c.f;
}
__device__ __forceinline__ float bfhi(uint u) {
    union { uint i; float f; } c; c.i = u & 0xffff0000u; return c.f;
}
// r = 1/(2^x + 1); caller folds tanh contribution as s += awk * r.
__device__ __forceinline__ float sigr(float x) {
    return __builtin_amdgcn_rcpf(__builtin_amdgcn_exp2f(x) + 1.0f);
}

// One-time: x -> bf16 B-frag order; Wp -> fp32 A-frag order (pre-scaled by
// 2*log2e); zero stats bins.  131072 threads, one uint2 out each.
__global__ __launch_bounds__(256) void prep_kernel(
    const float* __restrict__ x, const float* __restrict__ Wp,
    float* __restrict__ wpf, ushort* __restrict__ xbf, float* __restrict__ stats)
{
    const int tid = blockIdx.x * 256 + threadIdx.x;     // grid 512 -> 0..131071
    const int tid16 = tid >> 1, sub = tid & 1;          // old-uint4 id, half
    const int b = tid16 >> 12, rem = tid16 & 4095;
    const int jt = rem >> 7, ks = (rem >> 6) & 1, lane = rem & 63;
    const int qd = lane >> 4, ln = lane & 15;
    const float* __restrict__ src =
        x + ((size_t)(b * NN + jt * 16 + ln)) * DD + ks * 32 + qd * 8 + sub * 4;
    const float4 v = *(const float4*)src;
    uint2 o;
    o.x = pkbf2(v.x, v.y); o.y = pkbf2(v.z, v.w);
    ((uint2*)xbf)[tid] = o;                              // coalesced 8B
    if (tid < DD * DD) {
        const int oo = tid >> 6, d = tid & 63;
        const int mt = oo >> 4, l2 = oo & 15;
        const int k2 = d >> 5, q2 = (d >> 3) & 3, e = d & 7;
        wpf[(((mt * 2 + k2) * 64) + (q2 * 16 + l2)) * 8 + e] = Wp[tid] * K2LOG2E;
    }
    if (tid < NBIN * 128) stats[tid] = 0.0f;
}

// One block (256 thr, 4 waves) per (b,i); wave wv owns j-tiles wv*8..wv*8+7.
// XCD swizzle: b = (blk&7)*2 + ((blk>>3)&1), i = blk>>4.
// Computes agg, then the projection tail in-block -> pre-BN out + binned stats.
template <int MINW>
__global__ __launch_bounds__(256, MINW) void attn_kernel(
    const float* __restrict__ x,  const float* __restrict__ wpf,
    const ushort* __restrict__ xbf,
    const float* __restrict__ bp, const float* __restrict__ aw,
    const float* __restrict__ W1, const float* __restrict__ b1,
    const float* __restrict__ W2, const float* __restrict__ b2,
    float* __restrict__ out, float* __restrict__ stats)
{
    constexpr bool LDSAWK = (MINW >= 8);    // <8> path trades awk regs for LDS

    __shared__ float part[4][DD];                   // 1 KB
    __shared__ float s_esum[4];
    __shared__ __align__(16) float s_agg[DD], s_xi[DD];
    __shared__ __align__(16) float s_awk[DD];

    const int t = threadIdx.x;                      // 0..255
    const int wv = t >> 6, lane = t & 63;
    const int blk = blockIdx.x;                     // 0..8191
    const int b = (blk & 7) * 2 + ((blk >> 3) & 1); // XCD-local b
    const int i = blk >> 4;                         // 0..511
    const int row = b * NN + i;
    const int qd = lane >> 4, ln = lane & 15;
    const ushort* __restrict__ xb16 = xbf + (size_t)b * (NN * DD);
    const float* __restrict__ xrow = x + (size_t)row * DD;

    if (t < DD) {
        s_xi[t]  = xrow[t];                         // for the projection tail
        s_awk[t] = aw[t] * -K2LOG2E;                // for the LDSAWK path
    }
    if (LDSAWK) __syncthreads();                    // s_awk ready before loop

    // xi fragment straight from global (L1/L2-hot; per-quad broadcast)
    float xiv[2][8];
    #pragma unroll
    for (int ks = 0; ks < 2; ++ks) {
        const float4 a = *(const float4*)(xrow + ks * 32 + qd * 8);
        const float4 c = *(const float4*)(xrow + ks * 32 + qd * 8 + 4);
        xiv[ks][0]=a.x; xiv[ks][1]=a.y; xiv[ks][2]=a.z; xiv[ks][3]=a.w;
        xiv[ks][4]=c.x; xiv[ks][5]=c.y; xiv[ks][6]=c.z; xiv[ks][7]=c.w;
    }

    // bpk straight from global (256B, L1-hot across all blocks)
    float bpk[16];
    float awkr[16];                                 // register path only
    #pragma unroll
    for (int mt = 0; mt < 4; ++mt) {
        const float4 vb = *(const float4*)(bp + mt * 16 + qd * 4);
        bpk[mt*4+0] = vb.x * K2LOG2E; bpk[mt*4+1] = vb.y * K2LOG2E;
        bpk[mt*4+2] = vb.z * K2LOG2E; bpk[mt*4+3] = vb.w * K2LOG2E;
        if (!LDSAWK) {
            const float4 va = *(const float4*)(aw + mt * 16 + qd * 4);
            awkr[mt*4+0] = va.x * -K2LOG2E; awkr[mt*4+1] = va.y * -K2LOG2E;
            awkr[mt*4+2] = va.z * -K2LOG2E; awkr[mt*4+3] = va.w * -K2LOG2E;
        }
    }

    // A-frags: (2log2e * Wp) ⊙ xi in bf16, g = mt*2+ks
    bf16x8 afrag[8];
    #pragma unroll
    for (int g = 0; g < 8; ++g) {
        const int ks = g & 1;
        const float4 wa = *(const float4*)(wpf + (g * 64 + lane) * 8);
        const float4 wb = *(const float4*)(wpf + (g * 64 + lane) * 8 + 4);
        union { bf16x8 v; uint u[4]; } p;
        p.u[0] = pkbf2(wa.x * xiv[ks][0], wa.y * xiv[ks][1]);
        p.u[1] = pkbf2(wa.z * xiv[ks][2], wa.w * xiv[ks][3]);
        p.u[2] = pkbf2(wb.x * xiv[ks][4], wb.y * xiv[ks][5]);
        p.u[3] = pkbf2(wb.z * xiv[ks][6], wb.w * xiv[ks][7]);
        afrag[g] = p.v;
    }

    // ---- FUSED score + aggregate: 8 j-tiles for this wave ----
    float vacc[16];
    #pragma unroll
    for (int k = 0; k < 16; ++k) vacc[k] = 0.0f;
    float esum = 0.0f;

    #pragma unroll 4
    for (int tt = 0; tt < 8; ++tt) {
        const int tile = wv * 8 + tt;
        union { bf16x8 v; uint4 u; } b0, b1u;
        b0.v  = *(const bf16x8*)(xb16 + ((tile * 2 + 0) * 64 + lane) * 8);
        b1u.v = *(const bf16x8*)(xb16 + ((tile * 2 + 1) * 64 + lane) * 8);

        float s0 = 0.0f, s1 = 0.0f, s2 = 0.0f, s3 = 0.0f;
        #pragma unroll
        for (int mt = 0; mt < 4; ++mt) {
            f32x4 acc = { bpk[mt*4+0], bpk[mt*4+1], bpk[mt*4+2], bpk[mt*4+3] };
            acc = __builtin_amdgcn_mfma_f32_16x16x32_bf16(afrag[mt*2+0], b0.v,  acc, 0, 0, 0);
            acc = __builtin_amdgcn_mfma_f32_16x16x32_bf16(afrag[mt*2+1], b1u.v, acc, 0, 0, 0);
            if (LDSAWK) {
                // volatile: forbid LICM re-hoisting into 16 VGPRs
                const volatile float* va = s_awk + mt * 16 + qd * 4;
                s0 = fmaf(va[0], sigr(acc[0]), s0);
                s1 = fmaf(va[1], sigr(acc[1]), s1);
                s2 = fmaf(va[2], sigr(acc[2]), s2);
                s3 = fmaf(va[3], sigr(acc[3]), s3);
            } else {
                s0 = fmaf(awkr[mt*4+0], sigr(acc[0]), s0);
                s1 = fmaf(awkr[mt*4+1], sigr(acc[1]), s1);
                s2 = fmaf(awkr[mt*4+2], sigr(acc[2]), s2);
                s3 = fmaf(awkr[mt*4+3], sigr(acc[3]), s3);
            }
        }
        float sj = (s0 + s1) + (s2 + s3);
        sj += __shfl_xor(sj, 16);
        sj += __shfl_xor(sj, 32);        // all quads: exp2-arg for j = tile*16 + ln

        const float e = __builtin_amdgcn_exp2f(sj);   // log2e folded into awk
        esum += e;
        vacc[0]  = fmaf(e, bflo(b0.u.x),  vacc[0]);
        vacc[1]  = fmaf(e, bfhi(b0.u.x),  vacc[1]);
        vacc[2]  = fmaf(e, bflo(b0.u.y),  vacc[2]);
        vacc[3]  = fmaf(e, bfhi(b0.u.y),  vacc[3]);
        vacc[4]  = fmaf(e, bflo(b0.u.z),  vacc[4]);
        vacc[5]  = fmaf(e, bfhi(b0.u.z),  vacc[5]);
        vacc[6]  = fmaf(e, bflo(b0.u.w),  vacc[6]);
        vacc[7]  = fmaf(e, bfhi(b0.u.w),  vacc[7]);
        vacc[8]  = fmaf(e, bflo(b1u.u.x), vacc[8]);
        vacc[9]  = fmaf(e, bfhi(b1u.u.x), vacc[9]);
        vacc[10] = fmaf(e, bflo(b1u.u.y), vacc[10]);
        vacc[11] = fmaf(e, bfhi(b1u.u.y), vacc[11]);
        vacc[12] = fmaf(e, bflo(b1u.u.z), vacc[12]);
        vacc[13] = fmaf(e, bfhi(b1u.u.z), vacc[13]);
        vacc[14] = fmaf(e, bflo(b1u.u.w), vacc[14]);
        vacc[15] = fmaf(e, bfhi(b1u.u.w), vacc[15]);
    }

    // reduce over ln within wave
    #pragma unroll
    for (int off = 1; off < 16; off <<= 1) {
        esum += __shfl_xor(esum, off);
        #pragma unroll
        for (int k = 0; k < 16; ++k)
            vacc[k] += __shfl_xor(vacc[k], off);
    }
    if (lane == 0) s_esum[wv] = esum;
    if (ln == 0) {
        #pragma unroll
        for (int k = 0; k < 16; ++k)
            part[wv][(k >> 3) * 32 + qd * 8 + (k & 7)] = vacc[k];
    }
    __syncthreads();

    // block combine: agg[d] = (Σ_wv part[wv][d]) / (Σ_wv esum[wv]) -> s_agg
    if (t < DD) {
        const float tot = (s_esum[0] + s_esum[1]) + (s_esum[2] + s_esum[3]);
        const float inv = 1.0f / tot;
        const float a = (part[0][t] + part[1][t]) + (part[2][t] + part[3][t]);
        s_agg[t] = a * inv;
    }
    __syncthreads();

    // ---- projection tail (was proj_kernel) ----
    // thread (o = t>>2, qq = t&3): 16-d partial; W reads coalesced (wave =
    // 16 rows x 256B = 4KB contiguous); s_agg/s_xi reads are broadcasts.
    {
        const int o = t >> 2, qq = t & 3, d0 = qq * 16;
        const float* __restrict__ w1r = W1 + o * DD + d0;
        const float* __restrict__ w2r = W2 + o * DD + d0;
        float v = 0.0f;
        #pragma unroll
        for (int h = 0; h < 2; ++h) {       // 8 d's at a time, caps live regs
            const int dd = h * 8;
            const float4 wa  = *(const float4*)(w1r + dd);
            const float4 wa2 = *(const float4*)(w1r + dd + 4);
            const float4 ag  = *(const float4*)(s_agg + d0 + dd);
            const float4 ag2 = *(const float4*)(s_agg + d0 + dd + 4);
            v = fmaf(wa.x,  ag.x,  v); v = fmaf(wa.y,  ag.y,  v);
            v = fmaf(wa.z,  ag.z,  v); v = fmaf(wa.w,  ag.w,  v);
            v = fmaf(wa2.x, ag2.x, v); v = fmaf(wa2.y, ag2.y, v);
            v = fmaf(wa2.z, ag2.z, v); v = fmaf(wa2.w, ag2.w, v);
            const float4 wb  = *(const float4*)(w2r + dd);
            const float4 wb2 = *(const float4*)(w2r + dd + 4);
            const float4 xi  = *(const float4*)(s_xi + d0 + dd);
            const float4 xi2 = *(const float4*)(s_xi + d0 + dd + 4);
            v = fmaf(wb.x,  xi.x,  v); v = fmaf(wb.y,  xi.y,  v);
            v = fmaf(wb.z,  xi.z,  v); v = fmaf(wb.w,  xi.w,  v);
            v = fmaf(wb2.x, xi2.x, v); v = fmaf(wb2.y, xi2.y, v);
            v = fmaf(wb2.z, xi2.z, v); v = fmaf(wb2.w, xi2.w, v);
        }
        v += __shfl_xor(v, 1);
        v += __shfl_xor(v, 2);              // qq==0 lanes hold full 64-d sum
        if (qq == 0) {
            v += b1[o] + b2[o];
            out[(size_t)row * DD + o] = v;  // pre-BN x_out
            float* __restrict__ sb = stats + (blk & (NBIN - 1)) * 128;
            atomicAdd(&sb[o], v);
            atomicAdd(&sb[64 + o], v * v);
        }
    }
}

// BN (batch stats, biased var) + selu, IN PLACE on out; float4 I/O.
// Bin reduction parallel across 256 threads (16 bins each), LDS combine.
__global__ __launch_bounds__(256) void final_kernel(
    const float* __restrict__ stats,
    const float* __restrict__ gamma, const float* __restrict__ beta,
    float* __restrict__ out)
{
    __shared__ float red[2][128];
    __shared__ float smu[DD], sga[DD], sbe[DD];
    {
        const int slot = threadIdx.x & 127, grp = threadIdx.x >> 7;  // 0/1
        float s = 0.0f;
        #pragma unroll
        for (int bb = 0; bb < NBIN / 2; ++bb)
            s += stats[(grp * (NBIN / 2) + bb) * 128 + slot];
        red[grp][slot] = s;
    }
    __syncthreads();
    if (threadIdx.x < DD) {
        const int o = threadIdx.x;
        const float s1 = red[0][o] + red[1][o];
        const float s2 = red[0][64 + o] + red[1][64 + o];
        const float mean = s1 * (1.0f / BN_ROWS);
        const float var  = s2 * (1.0f / BN_ROWS) - mean * mean;
        smu[o] = mean;
        sga[o] = gamma[o] / sqrtf(var + 1e-5f);
        sbe[o] = beta[o];
    }
    __syncthreads();
    const int i4 = blockIdx.x * 256 + threadIdx.x;   // grid 512 -> exactly 131072
    const int o0 = (i4 & 15) * 4;
    const float4 v = ((const float4*)out)[i4];
    float r[4] = { v.x, v.y, v.z, v.w };
    #pragma unroll
    for (int c = 0; c < 4; ++c) {
        const float nrm = (r[c] - smu[o0 + c]) * sga[o0 + c] + sbe[o0 + c];
        r[c] = nrm > 0.0f
            ? 1.0507009873554805f * nrm
            : 1.7580993408473766f * expm1f(nrm);
    }
    ((float4*)out)[i4] = make_float4(r[0], r[1], r[2], r[3]);
}

extern "C" void kernel_launch(void* const* d_in, const int* in_sizes, int n_in,
                              void* d_out, int out_size, void* d_ws, size_t ws_size,
                              hipStream_t stream)
{
    const float* x  = (const float*)d_in[0];
    const float* Wp = (const float*)d_in[1];  // W_att_proj
    const float* bp = (const float*)d_in[2];  // b_att_proj
    const float* aw = (const float*)d_in[3];  // att_weight
    const float* W1 = (const float*)d_in[4];  // W_with
    const float* b1 = (const float*)d_in[5];  // b_with
    const float* W2 = (const float*)d_in[6];  // W_without
    const float* b2 = (const float*)d_in[7];  // b_without
    const float* ga = (const float*)d_in[8];  // gamma
    const float* be = (const float*)d_in[9];  // beta

    float*  stats = (float*)d_ws;                       // NBIN*128 floats (16KB)
    float*  wpf   = stats + NBIN * 128;                 // 4096 fp32 (A-frag order)
    ushort* xbf   = (ushort*)(wpf + DD * DD);           // 524288 bf16 (B-frag order)
    float*  out   = (float*)d_out;                      // fp32 output

    // cascade: highest min-waves instantiation that compiled spill-free.
    typedef void (*attn_fn)(const float*, const float*, const ushort*,
                            const float*, const float*,
                            const float*, const float*,
                            const float*, const float*,
                            float*, float*);
    static attn_fn chosen = nullptr;
    if (!chosen) {
        attn_fn cands[5] = { attn_kernel<8>, attn_kernel<7>, attn_kernel<6>,
                             attn_kernel<5>, attn_kernel<3> };
        chosen = cands[4];                 // safe default
        for (int c = 0; c < 5; ++c) {
            hipFuncAttributes fa;
            if (hipFuncGetAttributes(&fa,
                    reinterpret_cast<const void*>(cands[c])) == hipSuccess
                && fa.localSizeBytes == 0) {
                chosen = cands[c];
                break;
            }
        }
    }

    prep_kernel<<<512, 256, 0, stream>>>(x, Wp, wpf, xbf, stats);
    chosen<<<BN_ROWS, 256, 0, stream>>>(x, wpf, xbf, bp, aw, W1, b1, W2, b2, out, stats);
    final_kernel<<<512, 256, 0, stream>>>(stats, ga, be, out);
}